// Round 4
// baseline (271.449 us; speedup 1.0000x reference)
//
#include <hip/hip_runtime.h>
#include <hip/hip_cooperative_groups.h>
#include <math.h>

namespace cg = cooperative_groups;

// Problem constants
#define NB   4
#define CCH  256
#define HH   64
#define WW   64
#define GG   8
#define GCH  32
#define PP   9
#define HIN  66
#define WIN  66
#define HWSZ 4096            // H*W
#define NPIX 16384           // N*H*W

// Workspace element counts (ushort)
#define XP_ELEMS   (NB*HIN*WIN*CCH)     // 4460544
#define WINT_ELEMS (CCH*CCH)            // w_in^T  [n][k]
#define WOMT_ELEMS (216*CCH)            // [w_off|w_mask]^T [col][k]
#define WOUTT_ELEMS (CCH*CCH)           // w_out^T [n][k]

typedef __attribute__((ext_vector_type(8))) short bf16x8;
typedef __attribute__((ext_vector_type(4))) float f32x4;

__device__ __forceinline__ unsigned short f2bf(float f) {
    unsigned int u = __float_as_uint(f);
    unsigned int r = (u + 0x7FFFu + ((u >> 16) & 1u)) >> 16;
    return (unsigned short)r;
}
__device__ __forceinline__ float bf2f(unsigned short s) {
    return __uint_as_float(((unsigned int)s) << 16);
}

#define SDW_STRIDE 258
#define AGG_STRIDE 258

__device__ __forceinline__ void acc8_tap(float* a, uint4 vv, float wgt) {
    a[0] += wgt * __uint_as_float(vv.x << 16);
    a[1] += wgt * __uint_as_float(vv.x & 0xffff0000u);
    a[2] += wgt * __uint_as_float(vv.y << 16);
    a[3] += wgt * __uint_as_float(vv.y & 0xffff0000u);
    a[4] += wgt * __uint_as_float(vv.z << 16);
    a[5] += wgt * __uint_as_float(vv.z & 0xffff0000u);
    a[6] += wgt * __uint_as_float(vv.w << 16);
    a[7] += wgt * __uint_as_float(vv.w & 0xffff0000u);
}

// ---------------------------------------------------------------------------
// Single cooperative mega-kernel. 256 blocks x 1024 threads, 1 block/CU.
// Block b -> (n = b>>6, h = b&63): one image row of 64 pixels, all 256 ch.
// Phase A: weight transposes + xp ring zero            -> grid.sync
// Phase B: dw3x3 + LN + GELU + gemm_in(->xp global) + offmask(->LDS)
//          -> grid.sync (xp produced by all blocks)
// Phase C: deformable sampling for own 64 px (off/msk/agg in LDS)
// Phase D: agg @ wout^T + BN + SiLU -> out
// LDS: union(phaseB 74752, phaseC 97536) + off 37376 + msk 18944 = 153856 B
// ---------------------------------------------------------------------------
__global__ __launch_bounds__(1024) void k_mega(
    const float* __restrict__ x, const float* __restrict__ w_in,
    const float* __restrict__ b_in, const float* __restrict__ w_dw,
    const float* __restrict__ b_dw, const float* __restrict__ ln_g,
    const float* __restrict__ ln_b, const float* __restrict__ w_off,
    const float* __restrict__ b_off, const float* __restrict__ w_mask,
    const float* __restrict__ b_mask, const float* __restrict__ w_out,
    const float* __restrict__ b_out, const float* __restrict__ bn_g,
    const float* __restrict__ bn_b, const float* __restrict__ bn_mean,
    const float* __restrict__ bn_var, float* __restrict__ out,
    unsigned short* __restrict__ xp, unsigned short* __restrict__ win_t,
    unsigned short* __restrict__ womt, unsigned short* __restrict__ wout_t)
{
    cg::grid_group gridg = cg::this_grid();

    // ---- LDS layout ----
    __shared__ __align__(16) unsigned char smem_raw[97536];  // phase-union
    __shared__ float lds_off[64][146];   // persistent B->C (144 cols + pad)
    __shared__ float lds_msk[64][74];    // persistent B->C (72 cols + pad)

    // phase B views
    unsigned short* sdw = (unsigned short*)smem_raw;              // 33024 B
    unsigned short* sxr = sdw + 64 * SDW_STRIDE;                  // 33024 B
    float (*r1s)[64] = (float(*)[64])(smem_raw + 66048);          // 4096 B
    float (*r2s)[64] = (float(*)[64])(smem_raw + 70144);          // 4096 B
    float* mu_s = (float*)(smem_raw + 74240);                     // 256 B
    float* rs_s = (float*)(smem_raw + 74496);                     // 256 B
    // phase C/D views (overlay; valid after grid.sync post-B)
    unsigned short* agg_l = (unsigned short*)smem_raw;            // 33024 B
    float*  smx = (float*)(smem_raw + 33024);                     // 9216 B
    int2*   tco = (int2*)(smem_raw + 42240);                      // 18432 B
    float4* twt = (float4*)(smem_raw + 60672);                    // 36864 B

    const int b = blockIdx.x;
    const int tid = threadIdx.x;
    const int h = b & 63;
    const int n = b >> 6;

    // =========================== Phase A ===============================
    {
        const int i = b * 1024 + tid;
        if (i < 252928) {
            if (i < 65536) {
                int nn = i & 255, k = i >> 8;
                win_t[nn * 256 + k] = f2bf(w_in[i]);         // w_in[k][nn]
            } else if (i < 131072) {
                int j = i - 65536;
                int nn = j & 255, k = j >> 8;
                wout_t[nn * 256 + k] = f2bf(w_out[j]);
            } else if (i < 186368) {
                int j = i - 131072;
                int k = j / 216, col = j - k * 216;
                float v = (col < 144) ? w_off[k * 144 + col]
                                      : w_mask[k * 72 + col - 144];
                womt[col * 256 + k] = f2bf(v);
            } else {
                int r = i - 186368;                 // [0, 66560)
                int seg = r >> 6, ln = r & 63;
                int nn = seg / 260, rp = seg % 260;
                int hh, ww;
                if (rp < 66)       { hh = 0;        ww = rp; }
                else if (rp < 132) { hh = 65;       ww = rp - 66; }
                else if (rp < 196) { hh = rp - 131; ww = 0; }
                else               { hh = rp - 195; ww = 65; }
                uint2 z = make_uint2(0u, 0u);
                *(uint2*)&xp[(((size_t)nn * HIN + hh) * WIN + ww) * CCH + ln * 4] = z;
            }
        }
    }
    gridg.sync();

    // =========================== Phase B ===============================
    {
        const int wave = __builtin_amdgcn_readfirstlane(tid >> 6);   // 0..15
        const int lane = tid & 63;        // = w in dw phase

        const float* xn = x + (size_t)n * CCH * HWSZ;
        const bool h0ok = (h > 0);
        const bool h2ok = (h < HH - 1);

        float s1 = 0.f, s2 = 0.f;

        // ---- depthwise 3x3, 16 channels per wave ----
#pragma unroll 4
        for (int it = 0; it < 16; it++) {
            const int c = it * 16 + wave;
            const float* xc = xn + (size_t)c * HWSZ + h * WW + lane;
            float v0 = h0ok ? xc[-WW] : 0.f;
            float v1 = xc[0];
            float v2 = h2ok ? xc[WW] : 0.f;

            const float* wk = w_dw + c * 9;     // scalar (SMEM) loads
            float acc = b_dw[c];

            float l0 = __shfl_up(v0, 1);   if (lane == 0)  l0 = 0.f;
            float r0 = __shfl_down(v0, 1); if (lane == 63) r0 = 0.f;
            acc += wk[0] * l0 + wk[1] * v0 + wk[2] * r0;

            float l1 = __shfl_up(v1, 1);   if (lane == 0)  l1 = 0.f;
            float r1 = __shfl_down(v1, 1); if (lane == 63) r1 = 0.f;
            acc += wk[3] * l1 + wk[4] * v1 + wk[5] * r1;

            float l2 = __shfl_up(v2, 1);   if (lane == 0)  l2 = 0.f;
            float r2 = __shfl_down(v2, 1); if (lane == 63) r2 = 0.f;
            acc += wk[6] * l2 + wk[7] * v2 + wk[8] * r2;

            s1 += acc;
            s2 += acc * acc;
            sdw[lane * SDW_STRIDE + c] = f2bf(acc);
            sxr[lane * SDW_STRIDE + c] = f2bf(v1);
        }

        r1s[wave][lane] = s1;
        r2s[wave][lane] = s2;
        __syncthreads();

        // ---- LN stats per pixel ----
        if (tid < 64) {
            float a1 = 0.f, a2 = 0.f;
#pragma unroll
            for (int q = 0; q < 16; q++) { a1 += r1s[q][tid]; a2 += r2s[q][tid]; }
            float mu = a1 * (1.0f / 256.0f);
            float var = a2 * (1.0f / 256.0f) - mu * mu;
            mu_s[tid] = mu;
            rs_s[tid] = rsqrtf(var + 1e-5f);
        }
        __syncthreads();

        // ---- LN + GELU in-place into sdw ----
        {
            const int c0 = (tid & 63) * 4;
            float g4[4], b4[4];
#pragma unroll
            for (int i = 0; i < 4; i++) { g4[i] = ln_g[c0 + i]; b4[i] = ln_b[c0 + i]; }
#pragma unroll
            for (int pass = 0; pass < 4; pass++) {
                int w = wave + pass * 16;
                float mu = mu_s[w], rs = rs_s[w];
                unsigned short* row = &sdw[w * SDW_STRIDE + c0];
#pragma unroll
                for (int i = 0; i < 4; i++) {
                    float v = (bf2f(row[i]) - mu) * rs * g4[i] + b4[i];
                    row[i] = f2bf(0.5f * v * (1.0f + erff(v * 0.70710678118654752f)));
                }
            }
        }
        __syncthreads();

        // ---- fused GEMMs from LDS ----
        const int r16  = lane & 15;
        const int quad = lane >> 4;
        const int wm   = wave >> 2;       // m-tile 0..3 (16 pixels each)
        const int wn   = wave & 3;        // n-quarter (4 x 16 cols each)

#define LOAD_A(frag, basep, koff)                                   \
        {                                                           \
            const unsigned short* ap_ = (basep) + (koff);           \
            ((unsigned int*)&(frag))[0] = *(const unsigned int*)&ap_[0];\
            ((unsigned int*)&(frag))[1] = *(const unsigned int*)&ap_[2];\
            ((unsigned int*)&(frag))[2] = *(const unsigned int*)&ap_[4];\
            ((unsigned int*)&(frag))[3] = *(const unsigned int*)&ap_[6];\
        }

        // gemm_in: bf16(x) @ win_t^T + b_in -> xp interior (global)
        {
            f32x4 acc[4];
#pragma unroll
            for (int i = 0; i < 4; i++) acc[i] = (f32x4){0.f, 0.f, 0.f, 0.f};
            const unsigned short* arow = &sxr[(wm * 16 + r16) * SDW_STRIDE];

#pragma unroll
            for (int k0 = 0; k0 < CCH; k0 += 32) {
                bf16x8 a;
                LOAD_A(a, arow, k0 + quad * 8);
#pragma unroll
                for (int i = 0; i < 4; i++) {
                    int co = (wn * 4 + i) * 16 + r16;
                    bf16x8 bfr = *(const bf16x8*)&win_t[(size_t)co * CCH + k0 + quad * 8];
                    acc[i] = __builtin_amdgcn_mfma_f32_16x16x32_bf16(a, bfr, acc[i], 0, 0, 0);
                }
            }

            unsigned short* xprow = xp + (((size_t)n * HIN + (h + 1)) * WIN + 1) * CCH;
#pragma unroll
            for (int i = 0; i < 4; i++) {
                int co = (wn * 4 + i) * 16 + r16;
                float bias = b_in[co];
#pragma unroll
                for (int r = 0; r < 4; r++) {
                    int w = wm * 16 + quad * 4 + r;
                    xprow[(size_t)w * CCH + co] = f2bf(acc[i][r] + bias);
                }
            }
        }

        // offmask: x1 @ womt^T + bias -> lds_off / lds_msk
        {
            f32x4 acc[4];
#pragma unroll
            for (int i = 0; i < 4; i++) acc[i] = (f32x4){0.f, 0.f, 0.f, 0.f};
            const unsigned short* arow = &sdw[(wm * 16 + r16) * SDW_STRIDE];

#pragma unroll
            for (int k0 = 0; k0 < CCH; k0 += 32) {
                bf16x8 a;
                LOAD_A(a, arow, k0 + quad * 8);
#pragma unroll
                for (int i = 0; i < 4; i++) {
                    int col = (wn * 4 + i) * 16 + r16;
                    int colc = (col < 216) ? col : 215;   // clamp: safe addr
                    bf16x8 bfr = *(const bf16x8*)&womt[(size_t)colc * CCH + k0 + quad * 8];
                    acc[i] = __builtin_amdgcn_mfma_f32_16x16x32_bf16(a, bfr, acc[i], 0, 0, 0);
                }
            }

#pragma unroll
            for (int i = 0; i < 4; i++) {
                int col = (wn * 4 + i) * 16 + r16;
                if (col >= 216) continue;
                float bias = (col < 144) ? b_off[col] : b_mask[col - 144];
#pragma unroll
                for (int r = 0; r < 4; r++) {
                    int w = wm * 16 + quad * 4 + r;
                    float v = acc[i][r] + bias;
                    if (col < 144) lds_off[w][col] = v;
                    else           lds_msk[w][col - 144] = v;
                }
            }
        }
    }
    gridg.sync();   // xp fully produced grid-wide; frees sdw/sxr region

    // =========================== Phase C ===============================
    {
        const int sub  = tid >> 8;        // 0..3 (256-thread sub-group)
        const int stid = tid & 255;
        float*  smg = &smx[sub * 576];
        int2*   tcg = &tco[sub * 576];
        float4* twg = &twt[sub * 576];

        for (int chunk = 0; chunk < 2; ++chunk) {
            __syncthreads();
            const int lp0 = chunk * 32 + sub * 8;   // local pixel base (8 px)

            if (stid < 64) {
                const int pix = stid >> 3, g = stid & 7;
                const float* mskp = &lds_msk[lp0 + pix][g * 9];
                float e[9];
                float mx = -1e30f;
#pragma unroll
                for (int p = 0; p < PP; p++) { e[p] = mskp[p]; mx = fmaxf(mx, e[p]); }
                float sum = 0.f;
#pragma unroll
                for (int p = 0; p < PP; p++) { e[p] = __expf(e[p] - mx); sum += e[p]; }
                float rs = 1.0f / sum;
#pragma unroll
                for (int p = 0; p < PP; p++) smg[stid * 9 + p] = e[p] * rs;
            }
            __syncthreads();

            for (int idx = stid; idx < 576; idx += 256) {
                int pix = idx / 72;
                int rem = idx - pix * 72;
                int g = rem / 9;
                int p = rem - g * 9;
                int lp = lp0 + pix;
                int w = lp;                          // block = one (n,h) row
                const float* offp = &lds_off[lp][g * 18 + p * 2];
                float ox = offp[0], oy = offp[1];
                int i = p / 3, j = p - i * 3;
                float fx = (float)(w + i) + ox;
                float fy = (float)(h + j) + oy;
                float x0f = floorf(fx), y0f = floorf(fy);
                int x0 = (int)x0f, y0 = (int)y0f;
                float wx = fx - x0f, wy = fy - y0f;
                float m = smg[idx];
                float w00 = (1.f - wx) * (1.f - wy) * m;
                float w10 = wx * (1.f - wy) * m;
                float w01 = (1.f - wx) * wy * m;
                float w11 = wx * wy * m;
                int x1c = x0 + 1, y1c = y0 + 1;
                if (!((x0  >= 0) && (x0  < WIN))) { w00 = 0.f; w01 = 0.f; }
                if (!((x1c >= 0) && (x1c < WIN))) { w10 = 0.f; w11 = 0.f; }
                if (!((y0  >= 0) && (y0  < HIN))) { w00 = 0.f; w10 = 0.f; }
                if (!((y1c >= 0) && (y1c < HIN))) { w01 = 0.f; w11 = 0.f; }
                int cx0 = min(max(x0, 0), WIN - 1), cx1 = min(max(x1c, 0), WIN - 1);
                int cy0 = min(max(y0, 0), HIN - 1), cy1 = min(max(y1c, 0), HIN - 1);
                tcg[idx] = make_int2(cx0 | (cx1 << 16), cy0 | (cy1 << 16));
                twg[idx] = make_float4(w00, w10, w01, w11);
            }
            __syncthreads();

            {
                const int pix = stid >> 5;
                const int l5 = stid & 31;
                const int g = l5 >> 2, c8 = l5 & 3;
                const int lp = lp0 + pix;
                const unsigned short* base = xp + (size_t)n * HIN * WIN * CCH + g * GCH + c8 * 8;
                const int tbase = pix * 72 + g * 9;

                float a[8];
#pragma unroll
                for (int i = 0; i < 8; i++) a[i] = 0.f;

#pragma unroll
                for (int p = 0; p < PP; p++) {
                    int2 cc = tcg[tbase + p];
                    float4 wt = twg[tbase + p];
                    int cx0 = cc.x & 0xFFFF, cx1 = cc.x >> 16;
                    int cy0 = cc.y & 0xFFFF, cy1 = cc.y >> 16;
                    const unsigned short* r0 = base + (size_t)(cy0 * WIN) * CCH;
                    const unsigned short* r1 = base + (size_t)(cy1 * WIN) * CCH;
                    uint4 v00 = *(const uint4*)&r0[(size_t)cx0 * CCH];
                    uint4 v10 = *(const uint4*)&r0[(size_t)cx1 * CCH];
                    uint4 v01 = *(const uint4*)&r1[(size_t)cx0 * CCH];
                    uint4 v11 = *(const uint4*)&r1[(size_t)cx1 * CCH];
                    acc8_tap(a, v00, wt.x);
                    acc8_tap(a, v10, wt.y);
                    acc8_tap(a, v01, wt.z);
                    acc8_tap(a, v11, wt.w);
                }

                unsigned int* dst = (unsigned int*)&agg_l[lp * AGG_STRIDE + g * GCH + c8 * 8];
                dst[0] = (unsigned int)f2bf(a[0]) | ((unsigned int)f2bf(a[1]) << 16);
                dst[1] = (unsigned int)f2bf(a[2]) | ((unsigned int)f2bf(a[3]) << 16);
                dst[2] = (unsigned int)f2bf(a[4]) | ((unsigned int)f2bf(a[5]) << 16);
                dst[3] = (unsigned int)f2bf(a[6]) | ((unsigned int)f2bf(a[7]) << 16);
            }
        }
    }
    __syncthreads();   // agg_l complete for this block

    // =========================== Phase D ===============================
    {
        const int wave = tid >> 6;
        const int lane = tid & 63;
        const int r16  = lane & 15;
        const int quad = lane >> 4;
        const int wm   = wave >> 2;       // m-tile 0..3
        const int wn   = wave & 3;        // 64-col group

        f32x4 acc[4];
#pragma unroll
        for (int i = 0; i < 4; i++) acc[i] = (f32x4){0.f, 0.f, 0.f, 0.f};

        const unsigned short* arow = &agg_l[(wm * 16 + r16) * AGG_STRIDE];

#pragma unroll
        for (int k0 = 0; k0 < CCH; k0 += 32) {
            bf16x8 a;
            LOAD_A(a, arow, k0 + quad * 8);
#pragma unroll
            for (int nt = 0; nt < 4; nt++) {
                int co = wn * 64 + nt * 16 + r16;
                bf16x8 bfr = *(const bf16x8*)&wout_t[(size_t)co * CCH + k0 + quad * 8];
                acc[nt] = __builtin_amdgcn_mfma_f32_16x16x32_bf16(a, bfr, acc[nt], 0, 0, 0);
            }
        }
#undef LOAD_A

#pragma unroll
        for (int nt = 0; nt < 4; nt++) {
            int co = wn * 64 + nt * 16 + r16;
            float mean = bn_mean[co];
            float rstd = rsqrtf(bn_var[co] + 1e-5f);
            float gg = bn_g[co], bb = bn_b[co], bo = b_out[co];
            float tmp[4];
#pragma unroll
            for (int r = 0; r < 4; r++) {
                float y = acc[nt][r] + bo;
                float yh = (y - mean) * rstd * gg + bb;
                tmp[r] = yh / (1.0f + __expf(-yh));
            }
            float4 v = make_float4(tmp[0], tmp[1], tmp[2], tmp[3]);
            *(float4*)&out[((size_t)n * CCH + co) * HWSZ + h * WW + wm * 16 + quad * 4] = v;
        }
    }
}

// ---------------------------------------------------------------------------
extern "C" void kernel_launch(void* const* d_in, const int* in_sizes, int n_in,
                              void* d_out, int out_size, void* d_ws, size_t ws_size,
                              hipStream_t stream)
{
    const float* x       = (const float*)d_in[0];
    const float* w_in    = (const float*)d_in[1];
    const float* b_in    = (const float*)d_in[2];
    const float* w_dw    = (const float*)d_in[3];
    const float* b_dw    = (const float*)d_in[4];
    const float* ln_g    = (const float*)d_in[5];
    const float* ln_b    = (const float*)d_in[6];
    const float* w_off   = (const float*)d_in[7];
    const float* b_off   = (const float*)d_in[8];
    const float* w_mask  = (const float*)d_in[9];
    const float* b_mask  = (const float*)d_in[10];
    const float* w_out   = (const float*)d_in[11];
    const float* b_out   = (const float*)d_in[12];
    const float* bn_g    = (const float*)d_in[13];
    const float* bn_b    = (const float*)d_in[14];
    const float* bn_mean = (const float*)d_in[15];
    const float* bn_var  = (const float*)d_in[16];
    float* out = (float*)d_out;

    unsigned short* xp     = (unsigned short*)d_ws;
    unsigned short* win_t  = xp + XP_ELEMS;
    unsigned short* womt   = win_t + WINT_ELEMS;
    unsigned short* wout_t = womt + WOMT_ELEMS;
    // total ~9.3 MB workspace

    void* args[] = {
        (void*)&x, (void*)&w_in, (void*)&b_in, (void*)&w_dw, (void*)&b_dw,
        (void*)&ln_g, (void*)&ln_b, (void*)&w_off, (void*)&b_off,
        (void*)&w_mask, (void*)&b_mask, (void*)&w_out, (void*)&b_out,
        (void*)&bn_g, (void*)&bn_b, (void*)&bn_mean, (void*)&bn_var,
        (void*)&out, (void*)&xp, (void*)&win_t, (void*)&womt, (void*)&wout_t
    };
    hipLaunchCooperativeKernel((const void*)k_mega, dim3(256), dim3(1024),
                               args, 0, stream);
}

// Round 5
// 189.370 us; speedup vs baseline: 1.4334x; 1.4334x over previous
//
#include <hip/hip_runtime.h>
#include <math.h>

// Problem constants
#define NB   4
#define CCH  256
#define HH   64
#define WW   64
#define GG   8
#define GCH  32
#define PP   9
#define HIN  66
#define WIN  66
#define HWSZ 4096            // H*W
#define NPIX 16384           // N*H*W

// Workspace element counts (ushort unless noted)
#define XP_ELEMS   (NB*HIN*WIN*CCH)     // 4460544
#define AGG_ELEMS  (NPIX*CCH)           // 4194304
#define WINT_ELEMS (CCH*CCH)            // w_in^T  [n][k]
#define WOUTT_ELEMS (CCH*CCH)           // w_out^T [n][k]
#define WOMT_ELEMS (216*CCH)            // [w_off|w_mask]^T [col][k]
#define OFF_ELEMS  (NPIX*144)           // float
#define MSK_ELEMS  (NPIX*72)            // float

typedef __attribute__((ext_vector_type(8))) short bf16x8;
typedef __attribute__((ext_vector_type(4))) float f32x4;

__device__ __forceinline__ unsigned short f2bf(float f) {
    unsigned int u = __float_as_uint(f);
    unsigned int r = (u + 0x7FFFu + ((u >> 16) & 1u)) >> 16;
    return (unsigned short)r;
}
__device__ __forceinline__ float bf2f(unsigned short s) {
    return __uint_as_float(((unsigned int)s) << 16);
}

#define SDW_STRIDE 258

// ---------------------------------------------------------------------------
// Kernel 0: weight transposes (fp32 -> bf16, [n][k] layout) + xp ring zero.
// ---------------------------------------------------------------------------
__global__ __launch_bounds__(256) void k_prep(
    const float* __restrict__ w_in, const float* __restrict__ w_off,
    const float* __restrict__ w_mask, const float* __restrict__ w_out,
    unsigned short* __restrict__ win_t, unsigned short* __restrict__ womt,
    unsigned short* __restrict__ wout_t, unsigned short* __restrict__ xp)
{
    const int gtid = blockIdx.x * 256 + threadIdx.x;
    const int STRIDE = 128 * 256;         // 32768
    for (int i = gtid; i < 252928; i += STRIDE) {
        if (i < 65536) {
            int n = i & 255, k = i >> 8;
            win_t[n * 256 + k] = f2bf(w_in[i]);          // w_in[k][n]
        } else if (i < 131072) {
            int j = i - 65536;
            int n = j & 255, k = j >> 8;
            wout_t[n * 256 + k] = f2bf(w_out[j]);
        } else if (i < 186368) {
            int j = i - 131072;
            int k = j / 216, col = j - k * 216;
            float v = (col < 144) ? w_off[k * 144 + col]
                                  : w_mask[k * 72 + col - 144];
            womt[col * 256 + k] = f2bf(v);
        } else {
            int r = i - 186368;                 // [0, 66560)
            int seg = r >> 6, ln = r & 63;
            int n = seg / 260, rp = seg % 260;
            int h, w;
            if (rp < 66)       { h = 0;        w = rp; }
            else if (rp < 132) { h = 65;       w = rp - 66; }
            else if (rp < 196) { h = rp - 131; w = 0; }
            else               { h = rp - 195; w = 65; }
            uint2 z = make_uint2(0u, 0u);
            *(uint2*)&xp[(((size_t)n * HIN + h) * WIN + w) * CCH + ln * 4] = z;
        }
    }
}

// ---------------------------------------------------------------------------
// Kernel 1 (fused): depthwise 3x3 + LN + GELU, then both projections as
// per-block MFMA GEMMs straight from LDS (see R3 notes).
// 256 blocks x 1024 threads (16 waves).
// ---------------------------------------------------------------------------
__global__ __launch_bounds__(1024) void k_dw_fused(
    const float* __restrict__ x, const float* __restrict__ w_dw,
    const float* __restrict__ b_dw, const float* __restrict__ ln_g,
    const float* __restrict__ ln_b, const float* __restrict__ b_in,
    const unsigned short* __restrict__ win_t, const unsigned short* __restrict__ womt,
    const float* __restrict__ b_off, const float* __restrict__ b_mask,
    unsigned short* __restrict__ xp, float* __restrict__ off,
    float* __restrict__ msk)
{
    __shared__ unsigned short sdw[64 * SDW_STRIDE];   // conv result -> x1 (in-place)
    __shared__ unsigned short sxr[64 * SDW_STRIDE];   // raw x bf16   [w][c]
    __shared__ float r1s[16][64];
    __shared__ float r2s[16][64];
    __shared__ float mu_s[64];
    __shared__ float rs_s[64];

    const int b = blockIdx.x;
    const int tid = threadIdx.x;
    const int h = b & 63;
    const int n = b >> 6;
    const int wave = __builtin_amdgcn_readfirstlane(tid >> 6);   // 0..15, SGPR
    const int lane = tid & 63;        // = w in phase 1

    const float* xn = x + (size_t)n * CCH * HWSZ;
    const bool h0ok = (h > 0);
    const bool h2ok = (h < HH - 1);

    float s1 = 0.f, s2 = 0.f;

    // ---- phase 1: depthwise 3x3, 16 channels per wave ----
#pragma unroll 4
    for (int it = 0; it < 16; it++) {
        const int c = it * 16 + wave;
        const float* xc = xn + (size_t)c * HWSZ + h * WW + lane;
        float v0 = h0ok ? xc[-WW] : 0.f;
        float v1 = xc[0];
        float v2 = h2ok ? xc[WW] : 0.f;

        const float* wk = w_dw + c * 9;     // scalar (SMEM) loads
        float acc = b_dw[c];

        float l0 = __shfl_up(v0, 1);   if (lane == 0)  l0 = 0.f;
        float r0 = __shfl_down(v0, 1); if (lane == 63) r0 = 0.f;
        acc += wk[0] * l0 + wk[1] * v0 + wk[2] * r0;

        float l1 = __shfl_up(v1, 1);   if (lane == 0)  l1 = 0.f;
        float r1 = __shfl_down(v1, 1); if (lane == 63) r1 = 0.f;
        acc += wk[3] * l1 + wk[4] * v1 + wk[5] * r1;

        float l2 = __shfl_up(v2, 1);   if (lane == 0)  l2 = 0.f;
        float r2 = __shfl_down(v2, 1); if (lane == 63) r2 = 0.f;
        acc += wk[6] * l2 + wk[7] * v2 + wk[8] * r2;

        s1 += acc;
        s2 += acc * acc;
        sdw[lane * SDW_STRIDE + c] = f2bf(acc);
        sxr[lane * SDW_STRIDE + c] = f2bf(v1);
    }

    r1s[wave][lane] = s1;
    r2s[wave][lane] = s2;
    __syncthreads();

    // ---- phase 2: LN stats per pixel ----
    if (tid < 64) {
        float a1 = 0.f, a2 = 0.f;
#pragma unroll
        for (int q = 0; q < 16; q++) { a1 += r1s[q][tid]; a2 += r2s[q][tid]; }
        float mu = a1 * (1.0f / 256.0f);
        float var = a2 * (1.0f / 256.0f) - mu * mu;
        mu_s[tid] = mu;
        rs_s[tid] = rsqrtf(var + 1e-5f);
    }
    __syncthreads();

    // ---- phase 3: LN + GELU, in-place into sdw ----
    {
        const int c0 = (tid & 63) * 4;
        float g4[4], b4[4];
#pragma unroll
        for (int i = 0; i < 4; i++) { g4[i] = ln_g[c0 + i]; b4[i] = ln_b[c0 + i]; }
#pragma unroll
        for (int pass = 0; pass < 4; pass++) {
            int w = wave + pass * 16;
            float mu = mu_s[w], rs = rs_s[w];
            unsigned short* row = &sdw[w * SDW_STRIDE + c0];
#pragma unroll
            for (int i = 0; i < 4; i++) {
                float v = (bf2f(row[i]) - mu) * rs * g4[i] + b4[i];
                row[i] = f2bf(0.5f * v * (1.0f + erff(v * 0.70710678118654752f)));
            }
        }
    }
    __syncthreads();

    // ---- phase 4: fused GEMMs from LDS ----
    const int r16  = lane & 15;
    const int quad = lane >> 4;
    const int wm   = wave >> 2;       // m-tile 0..3 (16 pixels each)
    const int wn   = wave & 3;        // n-quarter (4 x 16 cols each)

#define LOAD_A(frag, basep, koff)                                   \
    {                                                               \
        const unsigned short* ap_ = (basep) + (koff);               \
        ((unsigned int*)&(frag))[0] = *(const unsigned int*)&ap_[0];\
        ((unsigned int*)&(frag))[1] = *(const unsigned int*)&ap_[2];\
        ((unsigned int*)&(frag))[2] = *(const unsigned int*)&ap_[4];\
        ((unsigned int*)&(frag))[3] = *(const unsigned int*)&ap_[6];\
    }

    // ---- gemm_in: bf16(x) @ win_t^T + b_in -> xp interior ----
    {
        f32x4 acc[4];
#pragma unroll
        for (int i = 0; i < 4; i++) acc[i] = (f32x4){0.f, 0.f, 0.f, 0.f};
        const unsigned short* arow = &sxr[(wm * 16 + r16) * SDW_STRIDE];

#pragma unroll
        for (int k0 = 0; k0 < CCH; k0 += 32) {
            bf16x8 a;
            LOAD_A(a, arow, k0 + quad * 8);
#pragma unroll
            for (int i = 0; i < 4; i++) {
                int co = (wn * 4 + i) * 16 + r16;
                bf16x8 bfr = *(const bf16x8*)&win_t[(size_t)co * CCH + k0 + quad * 8];
                acc[i] = __builtin_amdgcn_mfma_f32_16x16x32_bf16(a, bfr, acc[i], 0, 0, 0);
            }
        }

        unsigned short* xprow = xp + (((size_t)n * HIN + (h + 1)) * WIN + 1) * CCH;
#pragma unroll
        for (int i = 0; i < 4; i++) {
            int co = (wn * 4 + i) * 16 + r16;
            float bias = b_in[co];
#pragma unroll
            for (int r = 0; r < 4; r++) {
                int w = wm * 16 + quad * 4 + r;
                xprow[(size_t)w * CCH + co] = f2bf(acc[i][r] + bias);
            }
        }
    }

    // ---- offmask: x1 @ womt^T + bias -> off (fp32), msk (fp32) ----
    {
        f32x4 acc[4];
#pragma unroll
        for (int i = 0; i < 4; i++) acc[i] = (f32x4){0.f, 0.f, 0.f, 0.f};
        const unsigned short* arow = &sdw[(wm * 16 + r16) * SDW_STRIDE];

#pragma unroll
        for (int k0 = 0; k0 < CCH; k0 += 32) {
            bf16x8 a;
            LOAD_A(a, arow, k0 + quad * 8);
#pragma unroll
            for (int i = 0; i < 4; i++) {
                int col = (wn * 4 + i) * 16 + r16;
                int colc = (col < 216) ? col : 215;   // clamp: safe addr, result discarded
                bf16x8 bfr = *(const bf16x8*)&womt[(size_t)colc * CCH + k0 + quad * 8];
                acc[i] = __builtin_amdgcn_mfma_f32_16x16x32_bf16(a, bfr, acc[i], 0, 0, 0);
            }
        }

        const int sbase = n * HWSZ + h * WW;
#pragma unroll
        for (int i = 0; i < 4; i++) {
            int col = (wn * 4 + i) * 16 + r16;
            if (col >= 216) continue;
            float bias = (col < 144) ? b_off[col] : b_mask[col - 144];
#pragma unroll
            for (int r = 0; r < 4; r++) {
                int w = wm * 16 + quad * 4 + r;
                int s = sbase + w;
                float v = acc[i][r] + bias;
                if (col < 144) off[(size_t)s * 144 + col] = v;
                else           msk[(size_t)s * 72 + col - 144] = v;
            }
        }
    }
#undef LOAD_A
}

// ---------------------------------------------------------------------------
// Kernel 3: deformable sampling + aggregation, 8 px/block, 8 ch/lane (uint4)
// R5: XCD-aware block swizzle (T1). Default round-robin makes every XCD
// touch all 8.9 MB of xp (> 4 MB L2 -> L3/HBM latency taps). Swizzled,
// each XCD owns 256 contiguous blocks = half an image -> ~1.15 MB xp slice,
// L2-resident.
// ---------------------------------------------------------------------------
__device__ __forceinline__ void acc8_tap(float* a, uint4 vv, float wgt) {
    a[0] += wgt * __uint_as_float(vv.x << 16);
    a[1] += wgt * __uint_as_float(vv.x & 0xffff0000u);
    a[2] += wgt * __uint_as_float(vv.y << 16);
    a[3] += wgt * __uint_as_float(vv.y & 0xffff0000u);
    a[4] += wgt * __uint_as_float(vv.z << 16);
    a[5] += wgt * __uint_as_float(vv.z & 0xffff0000u);
    a[6] += wgt * __uint_as_float(vv.w << 16);
    a[7] += wgt * __uint_as_float(vv.w & 0xffff0000u);
}

__global__ __launch_bounds__(256) void k_sample_agg(
    const unsigned short* __restrict__ xp, const float* __restrict__ off,
    const float* __restrict__ msk, unsigned short* __restrict__ agg)
{
    __shared__ float  sm[576];
    __shared__ int2   tco[576];
    __shared__ float4 twt[576];

    const int tid = threadIdx.x;
    // XCD swizzle: 2048 blocks, 8 XCDs -> XCD k owns blocks [k*256,(k+1)*256)
    const int bid = blockIdx.x;
    const int bsw = (bid & 7) * 256 + (bid >> 3);
    const int s0 = bsw * 8;

    if (tid < 64) {
        const int pix = tid >> 3, g = tid & 7;
        const float* mskp = msk + (size_t)(s0 + pix) * 72 + g * 9;
        float e[9];
        float mx = -1e30f;
#pragma unroll
        for (int p = 0; p < PP; p++) { e[p] = mskp[p]; mx = fmaxf(mx, e[p]); }
        float sum = 0.f;
#pragma unroll
        for (int p = 0; p < PP; p++) { e[p] = __expf(e[p] - mx); sum += e[p]; }
        float rs = 1.0f / sum;
#pragma unroll
        for (int p = 0; p < PP; p++) sm[tid * 9 + p] = e[p] * rs;
    }
    __syncthreads();

    for (int idx = tid; idx < 576; idx += 256) {
        int pix = idx / 72;
        int rem = idx - pix * 72;
        int g = rem / 9;
        int p = rem - g * 9;
        int s = s0 + pix;
        int hw = s & 4095;
        int h = hw >> 6, w = hw & 63;
        const float* offp = off + (size_t)s * 144 + g * 18 + p * 2;
        float ox = offp[0], oy = offp[1];
        int i = p / 3, j = p - i * 3;
        float fx = (float)(w + i) + ox;
        float fy = (float)(h + j) + oy;
        float x0f = floorf(fx), y0f = floorf(fy);
        int x0 = (int)x0f, y0 = (int)y0f;
        float wx = fx - x0f, wy = fy - y0f;
        float m = sm[idx];
        float w00 = (1.f - wx) * (1.f - wy) * m;
        float w10 = wx * (1.f - wy) * m;
        float w01 = (1.f - wx) * wy * m;
        float w11 = wx * wy * m;
        int x1c = x0 + 1, y1c = y0 + 1;
        if (!((x0  >= 0) && (x0  < WIN))) { w00 = 0.f; w01 = 0.f; }
        if (!((x1c >= 0) && (x1c < WIN))) { w10 = 0.f; w11 = 0.f; }
        if (!((y0  >= 0) && (y0  < HIN))) { w00 = 0.f; w10 = 0.f; }
        if (!((y1c >= 0) && (y1c < HIN))) { w01 = 0.f; w11 = 0.f; }
        int cx0 = min(max(x0, 0), WIN - 1), cx1 = min(max(x1c, 0), WIN - 1);
        int cy0 = min(max(y0, 0), HIN - 1), cy1 = min(max(y1c, 0), HIN - 1);
        tco[idx] = make_int2(cx0 | (cx1 << 16), cy0 | (cy1 << 16));
        twt[idx] = make_float4(w00, w10, w01, w11);
    }
    __syncthreads();

    const int pix = tid >> 5;
    const int l5 = tid & 31;
    const int g = l5 >> 2, c8 = l5 & 3;
    const int s = s0 + pix;
    const int n = s >> 12;
    const unsigned short* base = xp + (size_t)n * HIN * WIN * CCH + g * GCH + c8 * 8;
    const int tbase = pix * 72 + g * 9;

    float a[8];
#pragma unroll
    for (int i = 0; i < 8; i++) a[i] = 0.f;

#pragma unroll
    for (int p = 0; p < PP; p++) {
        int2 cc = tco[tbase + p];
        float4 wt = twt[tbase + p];
        int cx0 = cc.x & 0xFFFF, cx1 = cc.x >> 16;
        int cy0 = cc.y & 0xFFFF, cy1 = cc.y >> 16;
        const unsigned short* r0 = base + (size_t)(cy0 * WIN) * CCH;
        const unsigned short* r1 = base + (size_t)(cy1 * WIN) * CCH;
        uint4 v00 = *(const uint4*)&r0[(size_t)cx0 * CCH];
        uint4 v10 = *(const uint4*)&r0[(size_t)cx1 * CCH];
        uint4 v01 = *(const uint4*)&r1[(size_t)cx0 * CCH];
        uint4 v11 = *(const uint4*)&r1[(size_t)cx1 * CCH];
        acc8_tap(a, v00, wt.x);
        acc8_tap(a, v10, wt.y);
        acc8_tap(a, v01, wt.z);
        acc8_tap(a, v11, wt.w);
    }

    uint4 o;
    o.x = (unsigned int)f2bf(a[0]) | ((unsigned int)f2bf(a[1]) << 16);
    o.y = (unsigned int)f2bf(a[2]) | ((unsigned int)f2bf(a[3]) << 16);
    o.z = (unsigned int)f2bf(a[4]) | ((unsigned int)f2bf(a[5]) << 16);
    o.w = (unsigned int)f2bf(a[6]) | ((unsigned int)f2bf(a[7]) << 16);
    *(uint4*)&agg[(size_t)s * CCH + g * GCH + c8 * 8] = o;
}

// ---------------------------------------------------------------------------
// Kernel 4: agg(bf16) @ wout_t^T + b_out -> BN -> SiLU -> out (NCHW fp32)
// R5: M-tile 128->64 px (grid 256x4 = 1024 blocks -> 16 waves/CU, was 8)
// + XCD swizzle so each XCD's agg slice (~1 MB) is L2-resident.
// ---------------------------------------------------------------------------
__global__ __launch_bounds__(256) void k_gemm_out(
    const unsigned short* __restrict__ agg, const unsigned short* __restrict__ wout_t,
    const float* __restrict__ b_out, const float* __restrict__ bn_g,
    const float* __restrict__ bn_b, const float* __restrict__ bn_mean,
    const float* __restrict__ bn_var, float* __restrict__ out)
{
    const int bx  = blockIdx.x;                  // 256
    const int bsw = (bx & 7) * 32 + (bx >> 3);   // XCD swizzle (256 = 8*32)
    const int m0  = bsw * 64;
    const int co0 = blockIdx.y * 64;
    const int tid = threadIdx.x;
    const int n   = m0 >> 12;
    const int hw0 = m0 & 4095;

    const int wave = tid >> 6;       // 0..3
    const int lane = tid & 63;
    const int r16  = lane & 15;
    const int quad = lane >> 4;
    const int mw   = wave * 16;      // 16-px m-tile per wave

    f32x4 acc[4];
#pragma unroll
    for (int j = 0; j < 4; j++) acc[j] = (f32x4){0.f, 0.f, 0.f, 0.f};

    const unsigned short* ap = agg + (size_t)(m0 + mw + r16) * CCH + quad * 8;

#pragma unroll
    for (int k0 = 0; k0 < CCH; k0 += 32) {
        bf16x8 a = *(const bf16x8*)&ap[k0];
#pragma unroll
        for (int nt = 0; nt < 4; nt++) {
            bf16x8 bfr = *(const bf16x8*)&wout_t[(size_t)(co0 + nt * 16 + r16) * CCH + k0 + quad * 8];
            acc[nt] = __builtin_amdgcn_mfma_f32_16x16x32_bf16(a, bfr, acc[nt], 0, 0, 0);
        }
    }

#pragma unroll
    for (int nt = 0; nt < 4; nt++) {
        int co = co0 + nt * 16 + r16;
        float mean = bn_mean[co];
        float rstd = rsqrtf(bn_var[co] + 1e-5f);
        float gg = bn_g[co], bb = bn_b[co], bo = b_out[co];
        int hwb = hw0 + mw + quad * 4;
        float tmp[4];
#pragma unroll
        for (int r = 0; r < 4; r++) {
            float y = acc[nt][r] + bo;
            float yh = (y - mean) * rstd * gg + bb;
            tmp[r] = yh / (1.0f + __expf(-yh));
        }
        float4 v = make_float4(tmp[0], tmp[1], tmp[2], tmp[3]);
        *(float4*)&out[((size_t)n * CCH + co) * HWSZ + hwb] = v;
    }
}

// ---------------------------------------------------------------------------
extern "C" void kernel_launch(void* const* d_in, const int* in_sizes, int n_in,
                              void* d_out, int out_size, void* d_ws, size_t ws_size,
                              hipStream_t stream)
{
    const float* x       = (const float*)d_in[0];
    const float* w_in    = (const float*)d_in[1];
    const float* b_in    = (const float*)d_in[2];
    const float* w_dw    = (const float*)d_in[3];
    const float* b_dw    = (const float*)d_in[4];
    const float* ln_g    = (const float*)d_in[5];
    const float* ln_b    = (const float*)d_in[6];
    const float* w_off   = (const float*)d_in[7];
    const float* b_off   = (const float*)d_in[8];
    const float* w_mask  = (const float*)d_in[9];
    const float* b_mask  = (const float*)d_in[10];
    const float* w_out   = (const float*)d_in[11];
    const float* b_out   = (const float*)d_in[12];
    const float* bn_g    = (const float*)d_in[13];
    const float* bn_b    = (const float*)d_in[14];
    const float* bn_mean = (const float*)d_in[15];
    const float* bn_var  = (const float*)d_in[16];
    float* out = (float*)d_out;

    unsigned short* xp     = (unsigned short*)d_ws;
    unsigned short* agg    = xp + XP_ELEMS;
    unsigned short* win_t  = agg + AGG_ELEMS;
    unsigned short* wout_t = win_t + WINT_ELEMS;
    unsigned short* womt   = wout_t + WOUTT_ELEMS;
    float* off = (float*)(womt + WOMT_ELEMS);
    float* msk = off + OFF_ELEMS;
    // total ~32 MB

    k_prep<<<dim3(128), 256, 0, stream>>>(w_in, w_off, w_mask, w_out,
                                          win_t, womt, wout_t, xp);
    k_dw_fused<<<dim3(256), 1024, 0, stream>>>(x, w_dw, b_dw, ln_g, ln_b, b_in,
                                               win_t, womt, b_off, b_mask,
                                               xp, off, msk);
    k_sample_agg<<<dim3(2048), 256, 0, stream>>>(xp, off, msk, agg);
    k_gemm_out<<<dim3(256, 4), 256, 0, stream>>>(agg, wout_t, b_out, bn_g, bn_b, bn_mean, bn_var, out);
}

// Round 6
// 183.041 us; speedup vs baseline: 1.4830x; 1.0346x over previous
//
#include <hip/hip_runtime.h>
#include <math.h>

// Problem constants
#define NB   4
#define CCH  256
#define HH   64
#define WW   64
#define GG   8
#define GCH  32
#define PP   9
#define HIN  66
#define WIN  66
#define HWSZ 4096            // H*W
#define NPIX 16384           // N*H*W

// Workspace element counts (ushort unless noted)
#define XP_ELEMS   (NB*HIN*WIN*CCH)     // 4460544
#define WINT_ELEMS (CCH*CCH)            // w_in^T  [n][k]
#define WOUTT_ELEMS (CCH*CCH)           // w_out^T [n][k]
#define WOMT_ELEMS (216*CCH)            // [w_off|w_mask]^T [col][k]
#define OFF_ELEMS  (NPIX*144)           // float
#define MSK_ELEMS  (NPIX*72)            // float

typedef __attribute__((ext_vector_type(8))) short bf16x8;
typedef __attribute__((ext_vector_type(4))) float f32x4;

__device__ __forceinline__ unsigned short f2bf(float f) {
    unsigned int u = __float_as_uint(f);
    unsigned int r = (u + 0x7FFFu + ((u >> 16) & 1u)) >> 16;
    return (unsigned short)r;
}
__device__ __forceinline__ float bf2f(unsigned short s) {
    return __uint_as_float(((unsigned int)s) << 16);
}

#define SDW_STRIDE 258

// ---------------------------------------------------------------------------
// Kernel 0: weight transposes (fp32 -> bf16, [n][k] layout) + xp ring zero.
// ---------------------------------------------------------------------------
__global__ __launch_bounds__(256) void k_prep(
    const float* __restrict__ w_in, const float* __restrict__ w_off,
    const float* __restrict__ w_mask, const float* __restrict__ w_out,
    unsigned short* __restrict__ win_t, unsigned short* __restrict__ womt,
    unsigned short* __restrict__ wout_t, unsigned short* __restrict__ xp)
{
    const int gtid = blockIdx.x * 256 + threadIdx.x;
    const int STRIDE = 128 * 256;         // 32768
    for (int i = gtid; i < 252928; i += STRIDE) {
        if (i < 65536) {
            int n = i & 255, k = i >> 8;
            win_t[n * 256 + k] = f2bf(w_in[i]);          // w_in[k][n]
        } else if (i < 131072) {
            int j = i - 65536;
            int n = j & 255, k = j >> 8;
            wout_t[n * 256 + k] = f2bf(w_out[j]);
        } else if (i < 186368) {
            int j = i - 131072;
            int k = j / 216, col = j - k * 216;
            float v = (col < 144) ? w_off[k * 144 + col]
                                  : w_mask[k * 72 + col - 144];
            womt[col * 256 + k] = f2bf(v);
        } else {
            int r = i - 186368;                 // [0, 66560)
            int seg = r >> 6, ln = r & 63;
            int n = seg / 260, rp = seg % 260;
            int h, w;
            if (rp < 66)       { h = 0;        w = rp; }
            else if (rp < 132) { h = 65;       w = rp - 66; }
            else if (rp < 196) { h = rp - 131; w = 0; }
            else               { h = rp - 195; w = 65; }
            uint2 z = make_uint2(0u, 0u);
            *(uint2*)&xp[(((size_t)n * HIN + h) * WIN + w) * CCH + ln * 4] = z;
        }
    }
}

// ---------------------------------------------------------------------------
// Kernel 1 (fused): depthwise 3x3 + LN + GELU + both projections (MFMA from
// LDS). R6 phase-1 restructure: float4 loads, 4 px/lane, 4 channels/wave-iter
// -> 12 fat loads per wave (was 48 thin), halos via 2 shfls/row, weights in
// LDS. MLP by construction.
// 256 blocks x 1024 threads (16 waves).
// ---------------------------------------------------------------------------
__global__ __launch_bounds__(1024) void k_dw_fused(
    const float* __restrict__ x, const float* __restrict__ w_dw,
    const float* __restrict__ b_dw, const float* __restrict__ ln_g,
    const float* __restrict__ ln_b, const float* __restrict__ b_in,
    const unsigned short* __restrict__ win_t, const unsigned short* __restrict__ womt,
    const float* __restrict__ b_off, const float* __restrict__ b_mask,
    unsigned short* __restrict__ xp, float* __restrict__ off,
    float* __restrict__ msk)
{
    __shared__ unsigned short sdw[64 * SDW_STRIDE];   // conv -> x1 (in-place)
    __shared__ unsigned short sxr[64 * SDW_STRIDE];   // raw x bf16 [w][c]
    __shared__ float rr1[64][65];
    __shared__ float rr2[64][65];
    __shared__ float mu_s[64];
    __shared__ float rs_s[64];
    __shared__ float swdw[2304];      // w_dw staged
    __shared__ float sbdw[256];       // b_dw staged

    const int b = blockIdx.x;
    const int tid = threadIdx.x;
    const int h = b & 63;
    const int n = b >> 6;
    const int wave = __builtin_amdgcn_readfirstlane(tid >> 6);   // 0..15
    const int lane = tid & 63;
    const int grp  = lane >> 4;       // 0..3  (channel sub-group)
    const int l16  = lane & 15;       // px-quad index (4 px each)

    // stage dw weights to LDS
    for (int i = tid; i < 2304; i += 1024) swdw[i] = w_dw[i];
    if (tid < 256) sbdw[tid] = b_dw[tid];
    __syncthreads();

    const float* xn = x + (size_t)n * CCH * HWSZ;
    const bool h0ok = (h > 0);
    const bool h2ok = (h < HH - 1);

    float s1q[4] = {0.f, 0.f, 0.f, 0.f};
    float s2q[4] = {0.f, 0.f, 0.f, 0.f};

    // ---- phase 1: depthwise 3x3. 4 channels/wave-iter, float4 px loads ----
#pragma unroll
    for (int it = 0; it < 4; it++) {
        const int c = it * 64 + wave * 4 + grp;
        const float* xr = xn + (size_t)c * HWSZ + h * WW + l16 * 4;
        float4 v1 = *(const float4*)xr;
        float4 v0 = h0ok ? *(const float4*)(xr - WW) : make_float4(0.f,0.f,0.f,0.f);
        float4 v2 = h2ok ? *(const float4*)(xr + WW) : make_float4(0.f,0.f,0.f,0.f);

        const float* wk = &swdw[c * 9];
        float accq[4];
        float bias = sbdw[c];
#pragma unroll
        for (int k = 0; k < 4; k++) accq[k] = bias;

#define CROW(v, wa, wb, wc)                                            \
        {                                                              \
            float wl = __shfl_up((v).w, 1);   if (l16 == 0)  wl = 0.f; \
            float wr = __shfl_down((v).x, 1); if (l16 == 15) wr = 0.f; \
            accq[0] += (wa) * wl    + (wb) * (v).x + (wc) * (v).y;     \
            accq[1] += (wa) * (v).x + (wb) * (v).y + (wc) * (v).z;     \
            accq[2] += (wa) * (v).y + (wb) * (v).z + (wc) * (v).w;     \
            accq[3] += (wa) * (v).z + (wb) * (v).w + (wc) * wr;        \
        }
        CROW(v0, wk[0], wk[1], wk[2]);
        CROW(v1, wk[3], wk[4], wk[5]);
        CROW(v2, wk[6], wk[7], wk[8]);
#undef CROW

        float xv[4] = {v1.x, v1.y, v1.z, v1.w};
#pragma unroll
        for (int k = 0; k < 4; k++) {
            s1q[k] += accq[k];
            s2q[k] += accq[k] * accq[k];
            sdw[(l16 * 4 + k) * SDW_STRIDE + c] = f2bf(accq[k]);
            sxr[(l16 * 4 + k) * SDW_STRIDE + c] = f2bf(xv[k]);
        }
    }

    {
        const int contrib = wave * 4 + grp;   // 0..63
#pragma unroll
        for (int k = 0; k < 4; k++) {
            rr1[l16 * 4 + k][contrib] = s1q[k];
            rr2[l16 * 4 + k][contrib] = s2q[k];
        }
    }
    __syncthreads();

    // ---- phase 2: LN stats per pixel ----
    if (tid < 64) {
        float a1 = 0.f, a2 = 0.f;
#pragma unroll
        for (int q = 0; q < 64; q++) { a1 += rr1[tid][q]; a2 += rr2[tid][q]; }
        float mu = a1 * (1.0f / 256.0f);
        float var = a2 * (1.0f / 256.0f) - mu * mu;
        mu_s[tid] = mu;
        rs_s[tid] = rsqrtf(var + 1e-5f);
    }
    __syncthreads();

    // ---- phase 3: LN + GELU, in-place into sdw ----
    {
        const int c0 = (tid & 63) * 4;
        float g4[4], b4[4];
#pragma unroll
        for (int i = 0; i < 4; i++) { g4[i] = ln_g[c0 + i]; b4[i] = ln_b[c0 + i]; }
#pragma unroll
        for (int pass = 0; pass < 4; pass++) {
            int w = wave + pass * 16;
            float mu = mu_s[w], rs = rs_s[w];
            unsigned short* row = &sdw[w * SDW_STRIDE + c0];
#pragma unroll
            for (int i = 0; i < 4; i++) {
                float v = (bf2f(row[i]) - mu) * rs * g4[i] + b4[i];
                row[i] = f2bf(0.5f * v * (1.0f + erff(v * 0.70710678118654752f)));
            }
        }
    }
    __syncthreads();

    // ---- phase 4: fused GEMMs from LDS ----
    const int r16  = lane & 15;
    const int quad = lane >> 4;
    const int wm   = wave >> 2;       // m-tile 0..3 (16 pixels each)
    const int wn   = wave & 3;        // n-quarter (4 x 16 cols each)

#define LOAD_A(frag, basep, koff)                                   \
    {                                                               \
        const unsigned short* ap_ = (basep) + (koff);               \
        ((unsigned int*)&(frag))[0] = *(const unsigned int*)&ap_[0];\
        ((unsigned int*)&(frag))[1] = *(const unsigned int*)&ap_[2];\
        ((unsigned int*)&(frag))[2] = *(const unsigned int*)&ap_[4];\
        ((unsigned int*)&(frag))[3] = *(const unsigned int*)&ap_[6];\
    }

    // gemm_in: bf16(x) @ win_t^T + b_in -> xp interior
    {
        f32x4 acc[4];
#pragma unroll
        for (int i = 0; i < 4; i++) acc[i] = (f32x4){0.f, 0.f, 0.f, 0.f};
        const unsigned short* arow = &sxr[(wm * 16 + r16) * SDW_STRIDE];

#pragma unroll
        for (int k0 = 0; k0 < CCH; k0 += 32) {
            bf16x8 a;
            LOAD_A(a, arow, k0 + quad * 8);
#pragma unroll
            for (int i = 0; i < 4; i++) {
                int co = (wn * 4 + i) * 16 + r16;
                bf16x8 bfr = *(const bf16x8*)&win_t[(size_t)co * CCH + k0 + quad * 8];
                acc[i] = __builtin_amdgcn_mfma_f32_16x16x32_bf16(a, bfr, acc[i], 0, 0, 0);
            }
        }

        unsigned short* xprow = xp + (((size_t)n * HIN + (h + 1)) * WIN + 1) * CCH;
#pragma unroll
        for (int i = 0; i < 4; i++) {
            int co = (wn * 4 + i) * 16 + r16;
            float bias = b_in[co];
#pragma unroll
            for (int r = 0; r < 4; r++) {
                int w = wm * 16 + quad * 4 + r;
                xprow[(size_t)w * CCH + co] = f2bf(acc[i][r] + bias);
            }
        }
    }

    // offmask: x1 @ womt^T + bias -> off (fp32), msk (fp32)
    {
        f32x4 acc[4];
#pragma unroll
        for (int i = 0; i < 4; i++) acc[i] = (f32x4){0.f, 0.f, 0.f, 0.f};
        const unsigned short* arow = &sdw[(wm * 16 + r16) * SDW_STRIDE];

#pragma unroll
        for (int k0 = 0; k0 < CCH; k0 += 32) {
            bf16x8 a;
            LOAD_A(a, arow, k0 + quad * 8);
#pragma unroll
            for (int i = 0; i < 4; i++) {
                int col = (wn * 4 + i) * 16 + r16;
                int colc = (col < 216) ? col : 215;   // clamp: safe addr
                bf16x8 bfr = *(const bf16x8*)&womt[(size_t)colc * CCH + k0 + quad * 8];
                acc[i] = __builtin_amdgcn_mfma_f32_16x16x32_bf16(a, bfr, acc[i], 0, 0, 0);
            }
        }

        const int sbase = n * HWSZ + h * WW;
#pragma unroll
        for (int i = 0; i < 4; i++) {
            int col = (wn * 4 + i) * 16 + r16;
            if (col >= 216) continue;
            float bias = (col < 144) ? b_off[col] : b_mask[col - 144];
#pragma unroll
            for (int r = 0; r < 4; r++) {
                int w = wm * 16 + quad * 4 + r;
                int s = sbase + w;
                float v = acc[i][r] + bias;
                if (col < 144) off[(size_t)s * 144 + col] = v;
                else           msk[(size_t)s * 72 + col - 144] = v;
            }
        }
    }
#undef LOAD_A
}

// ---------------------------------------------------------------------------
// Kernel 2 (merged): deformable sampling -> agg in LDS -> output GEMM + BN
// + SiLU. 512 blocks x 512 threads, 32 px/block, 2 blocks/CU (LDS 71.8 KB).
// Saves a launch + the 16 MB agg global round-trip + the standalone GEMM's
// exposed A-load latency.
// ---------------------------------------------------------------------------
__device__ __forceinline__ void acc8_tap(float* a, uint4 vv, float wgt) {
    a[0] += wgt * __uint_as_float(vv.x << 16);
    a[1] += wgt * __uint_as_float(vv.x & 0xffff0000u);
    a[2] += wgt * __uint_as_float(vv.y << 16);
    a[3] += wgt * __uint_as_float(vv.y & 0xffff0000u);
    a[4] += wgt * __uint_as_float(vv.z << 16);
    a[5] += wgt * __uint_as_float(vv.z & 0xffff0000u);
    a[6] += wgt * __uint_as_float(vv.w << 16);
    a[7] += wgt * __uint_as_float(vv.w & 0xffff0000u);
}

__global__ __launch_bounds__(512) void k_samp_out(
    const unsigned short* __restrict__ xp, const float* __restrict__ off,
    const float* __restrict__ msk, const unsigned short* __restrict__ wout_t,
    const float* __restrict__ b_out, const float* __restrict__ bn_g,
    const float* __restrict__ bn_b, const float* __restrict__ bn_mean,
    const float* __restrict__ bn_var, float* __restrict__ out)
{
    __shared__ int2   tco[2304];                 // 18432 B
    __shared__ float4 twt[2304];                 // 36864 B
    __shared__ unsigned short agg_l[32 * SDW_STRIDE];  // 16512 B

    const int tid = threadIdx.x;
    const int s0 = blockIdx.x * 32;
    const int n = s0 >> 12;
    const int hw0 = s0 & 4095;

    // ---- phase P: per-(pix,g) softmax + tap prep (threads 0..255) ----
    if (tid < 256) {
        const int pix = tid >> 3, g = tid & 7;
        const int s = s0 + pix;
        const int hw = s & 4095;
        const int h = hw >> 6, w = hw & 63;
        const float* mskp = msk + (size_t)s * 72 + g * 9;
        const float* offp = off + (size_t)s * 144 + g * 18;
        float e[9];
        float mx = -1e30f;
#pragma unroll
        for (int p = 0; p < PP; p++) { e[p] = mskp[p]; mx = fmaxf(mx, e[p]); }
        float sum = 0.f;
#pragma unroll
        for (int p = 0; p < PP; p++) { e[p] = __expf(e[p] - mx); sum += e[p]; }
        float rs = 1.0f / sum;
#pragma unroll
        for (int p = 0; p < PP; p++) {
            float m = e[p] * rs;
            float ox = offp[p * 2], oy = offp[p * 2 + 1];
            int i = p / 3, j = p - i * 3;
            float fx = (float)(w + i) + ox;
            float fy = (float)(h + j) + oy;
            float x0f = floorf(fx), y0f = floorf(fy);
            int x0 = (int)x0f, y0 = (int)y0f;
            float wx = fx - x0f, wy = fy - y0f;
            float w00 = (1.f - wx) * (1.f - wy) * m;
            float w10 = wx * (1.f - wy) * m;
            float w01 = (1.f - wx) * wy * m;
            float w11 = wx * wy * m;
            int x1c = x0 + 1, y1c = y0 + 1;
            if (!((x0  >= 0) && (x0  < WIN))) { w00 = 0.f; w01 = 0.f; }
            if (!((x1c >= 0) && (x1c < WIN))) { w10 = 0.f; w11 = 0.f; }
            if (!((y0  >= 0) && (y0  < HIN))) { w00 = 0.f; w10 = 0.f; }
            if (!((y1c >= 0) && (y1c < HIN))) { w01 = 0.f; w11 = 0.f; }
            int cx0 = min(max(x0, 0), WIN - 1), cx1 = min(max(x1c, 0), WIN - 1);
            int cy0 = min(max(y0, 0), HIN - 1), cy1 = min(max(y1c, 0), HIN - 1);
            tco[tid * 9 + p] = make_int2(cx0 | (cx1 << 16), cy0 | (cy1 << 16));
            twt[tid * 9 + p] = make_float4(w00, w10, w01, w11);
        }
    }
    __syncthreads();

    // ---- phase T: taps, 2 passes of 16 px ----
    const int l5 = tid & 31;
    const int g = l5 >> 2, c8 = l5 & 3;
    const unsigned short* base = xp + (size_t)n * HIN * WIN * CCH + g * GCH + c8 * 8;

#pragma unroll
    for (int pp = 0; pp < 2; pp++) {
        const int pix = pp * 16 + (tid >> 5);
        const int tbase = pix * 72 + g * 9;

        float a[8];
#pragma unroll
        for (int i = 0; i < 8; i++) a[i] = 0.f;

#pragma unroll
        for (int p = 0; p < PP; p++) {
            int2 cc = tco[tbase + p];
            float4 wt = twt[tbase + p];
            int cx0 = cc.x & 0xFFFF, cx1 = cc.x >> 16;
            int cy0 = cc.y & 0xFFFF, cy1 = cc.y >> 16;
            const unsigned short* r0 = base + (size_t)(cy0 * WIN) * CCH;
            const unsigned short* r1 = base + (size_t)(cy1 * WIN) * CCH;
            uint4 v00 = *(const uint4*)&r0[(size_t)cx0 * CCH];
            uint4 v10 = *(const uint4*)&r0[(size_t)cx1 * CCH];
            uint4 v01 = *(const uint4*)&r1[(size_t)cx0 * CCH];
            uint4 v11 = *(const uint4*)&r1[(size_t)cx1 * CCH];
            acc8_tap(a, v00, wt.x);
            acc8_tap(a, v10, wt.y);
            acc8_tap(a, v01, wt.z);
            acc8_tap(a, v11, wt.w);
        }

        unsigned int* dst = (unsigned int*)&agg_l[pix * SDW_STRIDE + g * GCH + c8 * 8];
        dst[0] = (unsigned int)f2bf(a[0]) | ((unsigned int)f2bf(a[1]) << 16);
        dst[1] = (unsigned int)f2bf(a[2]) | ((unsigned int)f2bf(a[3]) << 16);
        dst[2] = (unsigned int)f2bf(a[4]) | ((unsigned int)f2bf(a[5]) << 16);
        dst[3] = (unsigned int)f2bf(a[6]) | ((unsigned int)f2bf(a[7]) << 16);
    }
    __syncthreads();

    // ---- phase G: 32x256 GEMM from LDS-agg + BN + SiLU -> out ----
    {
        const int wave = tid >> 6;        // 0..7
        const int lane = tid & 63;
        const int r16  = lane & 15;
        const int quad = lane >> 4;
        const int wm   = wave >> 2;       // m-tile 0..1 (16 px each)
        const int wn   = wave & 3;        // 64-col group

        f32x4 acc[4];
#pragma unroll
        for (int i = 0; i < 4; i++) acc[i] = (f32x4){0.f, 0.f, 0.f, 0.f};

        const unsigned short* arow = &agg_l[(wm * 16 + r16) * SDW_STRIDE];

#pragma unroll
        for (int k0 = 0; k0 < CCH; k0 += 32) {
            bf16x8 a;
            {
                const unsigned short* ap_ = arow + k0 + quad * 8;
                ((unsigned int*)&a)[0] = *(const unsigned int*)&ap_[0];
                ((unsigned int*)&a)[1] = *(const unsigned int*)&ap_[2];
                ((unsigned int*)&a)[2] = *(const unsigned int*)&ap_[4];
                ((unsigned int*)&a)[3] = *(const unsigned int*)&ap_[6];
            }
#pragma unroll
            for (int nt = 0; nt < 4; nt++) {
                int co = wn * 64 + nt * 16 + r16;
                bf16x8 bfr = *(const bf16x8*)&wout_t[(size_t)co * CCH + k0 + quad * 8];
                acc[nt] = __builtin_amdgcn_mfma_f32_16x16x32_bf16(a, bfr, acc[nt], 0, 0, 0);
            }
        }

#pragma unroll
        for (int nt = 0; nt < 4; nt++) {
            int co = wn * 64 + nt * 16 + r16;
            float mean = bn_mean[co];
            float rstd = rsqrtf(bn_var[co] + 1e-5f);
            float gg = bn_g[co], bb = bn_b[co], bo = b_out[co];
            int hwb = hw0 + wm * 16 + quad * 4;
            float tmp[4];
#pragma unroll
            for (int r = 0; r < 4; r++) {
                float y = acc[nt][r] + bo;
                float yh = (y - mean) * rstd * gg + bb;
                tmp[r] = yh / (1.0f + __expf(-yh));
            }
            float4 v = make_float4(tmp[0], tmp[1], tmp[2], tmp[3]);
            *(float4*)&out[((size_t)n * CCH + co) * HWSZ + hwb] = v;
        }
    }
}

// ---------------------------------------------------------------------------
extern "C" void kernel_launch(void* const* d_in, const int* in_sizes, int n_in,
                              void* d_out, int out_size, void* d_ws, size_t ws_size,
                              hipStream_t stream)
{
    const float* x       = (const float*)d_in[0];
    const float* w_in    = (const float*)d_in[1];
    const float* b_in    = (const float*)d_in[2];
    const float* w_dw    = (const float*)d_in[3];
    const float* b_dw    = (const float*)d_in[4];
    const float* ln_g    = (const float*)d_in[5];
    const float* ln_b    = (const float*)d_in[6];
    const float* w_off   = (const float*)d_in[7];
    const float* b_off   = (const float*)d_in[8];
    const float* w_mask  = (const float*)d_in[9];
    const float* b_mask  = (const float*)d_in[10];
    const float* w_out   = (const float*)d_in[11];
    const float* b_out   = (const float*)d_in[12];
    const float* bn_g    = (const float*)d_in[13];
    const float* bn_b    = (const float*)d_in[14];
    const float* bn_mean = (const float*)d_in[15];
    const float* bn_var  = (const float*)d_in[16];
    float* out = (float*)d_out;

    unsigned short* xp     = (unsigned short*)d_ws;
    unsigned short* win_t  = xp + XP_ELEMS;
    unsigned short* wout_t = win_t + WINT_ELEMS;
    unsigned short* womt   = wout_t + WOUTT_ELEMS;
    float* off = (float*)(womt + WOMT_ELEMS);
    float* msk = off + OFF_ELEMS;
    // total ~24 MB

    k_prep<<<dim3(128), 256, 0, stream>>>(w_in, w_off, w_mask, w_out,
                                          win_t, womt, wout_t, xp);
    k_dw_fused<<<dim3(256), 1024, 0, stream>>>(x, w_dw, b_dw, ln_g, ln_b, b_in,
                                               win_t, womt, b_off, b_mask,
                                               xp, off, msk);
    k_samp_out<<<dim3(512), 512, 0, stream>>>(xp, off, msk, wout_t, b_out,
                                              bn_g, bn_b, bn_mean, bn_var, out);
}

// Round 8
// 178.323 us; speedup vs baseline: 1.5222x; 1.0265x over previous
//
#include <hip/hip_runtime.h>
#include <math.h>

// Problem constants
#define NB   4
#define CCH  256
#define HH   64
#define WW   64
#define GG   8
#define GCH  32
#define PP   9
#define HIN  66
#define WIN  66
#define HWSZ 4096            // H*W
#define NPIX 16384           // N*H*W

// Workspace element counts (ushort unless noted)
#define XP_ELEMS   (NB*HIN*WIN*CCH)     // 4460544
#define WINT_ELEMS (CCH*CCH)            // w_in^T  [n][k]
#define WOUTT_ELEMS (CCH*CCH)           // w_out^T [n][k]
#define WOMT_ELEMS (216*CCH)            // [w_off|w_mask]^T [col][k]
#define OFF_ELEMS  (NPIX*144)           // float
#define MSK_ELEMS  (NPIX*72)            // float

typedef __attribute__((ext_vector_type(8))) short bf16x8;
typedef __attribute__((ext_vector_type(4))) float f32x4;

__device__ __forceinline__ unsigned short f2bf(float f) {
    unsigned int u = __float_as_uint(f);
    unsigned int r = (u + 0x7FFFu + ((u >> 16) & 1u)) >> 16;
    return (unsigned short)r;
}
__device__ __forceinline__ float bf2f(unsigned short s) {
    return __uint_as_float(((unsigned int)s) << 16);
}

// async global->LDS, 4B per lane. src is PER-LANE address; dst is wave-uniform
// LDS base (HW writes dst + lane*4).
typedef const __attribute__((address_space(1))) void cgvoid;
typedef __attribute__((address_space(3))) void lvoid;
__device__ __forceinline__ void gload_lds4(const float* g, float* l) {
    __builtin_amdgcn_global_load_lds((cgvoid*)g, (lvoid*)l, 4, 0, 0);
}

#define SDW_STRIDE 258

// ---------------------------------------------------------------------------
// Kernel 0: weight transposes (fp32 -> bf16, [n][k] layout) + xp ring zero.
// ---------------------------------------------------------------------------
__global__ __launch_bounds__(256) void k_prep(
    const float* __restrict__ w_in, const float* __restrict__ w_off,
    const float* __restrict__ w_mask, const float* __restrict__ w_out,
    unsigned short* __restrict__ win_t, unsigned short* __restrict__ womt,
    unsigned short* __restrict__ wout_t, unsigned short* __restrict__ xp)
{
    const int gtid = blockIdx.x * 256 + threadIdx.x;
    const int STRIDE = 128 * 256;         // 32768
    for (int i = gtid; i < 252928; i += STRIDE) {
        if (i < 65536) {
            int n = i & 255, k = i >> 8;
            win_t[n * 256 + k] = f2bf(w_in[i]);          // w_in[k][n]
        } else if (i < 131072) {
            int j = i - 65536;
            int n = j & 255, k = j >> 8;
            wout_t[n * 256 + k] = f2bf(w_out[j]);
        } else if (i < 186368) {
            int j = i - 131072;
            int k = j / 216, col = j - k * 216;
            float v = (col < 144) ? w_off[k * 144 + col]
                                  : w_mask[k * 72 + col - 144];
            womt[col * 256 + k] = f2bf(v);
        } else {
            int r = i - 186368;                 // [0, 66560)
            int seg = r >> 6, ln = r & 63;
            int n = seg / 260, rp = seg % 260;
            int h, w;
            if (rp < 66)       { h = 0;        w = rp; }
            else if (rp < 132) { h = 65;       w = rp - 66; }
            else if (rp < 196) { h = rp - 131; w = 0; }
            else               { h = rp - 195; w = 65; }
            uint2 z = make_uint2(0u, 0u);
            *(uint2*)&xp[(((size_t)n * HIN + h) * WIN + w) * CCH + ln * 4] = z;
        }
    }
}

// ---------------------------------------------------------------------------
// Kernel 1 (fused): depthwise 3x3 + LN + GELU + both projections (MFMA from
// LDS). R8: phase 1 uses global_load_lds double-buffering with DRAIN-FIRST
// vmcnt(0) (no counting assumptions -> race-free by construction; R7's
// counted vmcnt(6) failed correctness). Chunk ck+1 flies during conv of
// chunk ck; next iteration's vmcnt(0) drains before its buffer is read.
// Weights staged in LDS so the loop contains ONLY our 6 VMEM ops per chunk.
// 256 blocks x 1024 threads (16 waves). LDS ~131 KB -> 1 block/CU.
// ---------------------------------------------------------------------------
__global__ __launch_bounds__(1024) void k_dw_fused(
    const float* __restrict__ x, const float* __restrict__ w_dw,
    const float* __restrict__ b_dw, const float* __restrict__ ln_g,
    const float* __restrict__ ln_b, const float* __restrict__ b_in,
    const unsigned short* __restrict__ win_t, const unsigned short* __restrict__ womt,
    const float* __restrict__ b_off, const float* __restrict__ b_mask,
    unsigned short* __restrict__ xp, float* __restrict__ off,
    float* __restrict__ msk)
{
    __shared__ float xstage[2][32][3][64];            // 49152 B staged x rows
    __shared__ unsigned short sdw[64 * SDW_STRIDE];   // conv -> x1 (in-place)
    __shared__ unsigned short sxr[64 * SDW_STRIDE];   // raw x bf16 [w][c]
    __shared__ float r1s[16][64];
    __shared__ float r2s[16][64];
    __shared__ float mu_s[64];
    __shared__ float rs_s[64];
    __shared__ float swdw[2304];      // w_dw staged (kills VMEM in the loop)
    __shared__ float sbdw[256];

    const int b = blockIdx.x;
    const int tid = threadIdx.x;
    const int h = b & 63;
    const int n = b >> 6;
    const int wave = __builtin_amdgcn_readfirstlane(tid >> 6);   // 0..15, SGPR
    const int lane = tid & 63;        // = w (pixel) in phase 1

    // stage dw weights to LDS (normal loads; fully drained at the barrier)
    for (int i = tid; i < 2304; i += 1024) swdw[i] = w_dw[i];
    if (tid < 256) sbdw[tid] = b_dw[tid];
    __syncthreads();

    const float* xn = x + (size_t)n * CCH * HWSZ;
    const bool h0ok = (h > 0);
    const bool h2ok = (h < HH - 1);
    const int d0 = h0ok ? -WW : 0;    // dummy-safe halo offsets
    const int d2 = h2ok ?  WW : 0;

    // per-wave issue of chunk ck into buffer bb: 6 row loads (2ch x 3 rows)
#define ISSUE(ck, bb)                                                   \
    {                                                                   \
        const int cA_ = (ck) * 32 + wave * 2;                           \
        const float* gA_ = xn + (size_t)cA_ * HWSZ + h * WW + lane;     \
        const float* gB_ = gA_ + HWSZ;                                  \
        float* dA_ = &xstage[bb][wave * 2][0][0];                       \
        float* dB_ = &xstage[bb][wave * 2 + 1][0][0];                   \
        gload_lds4(gA_ + d0, dA_);                                      \
        gload_lds4(gA_,      dA_ + 64);                                 \
        gload_lds4(gA_ + d2, dA_ + 128);                                \
        gload_lds4(gB_ + d0, dB_);                                      \
        gload_lds4(gB_,      dB_ + 64);                                 \
        gload_lds4(gB_ + d2, dB_ + 128);                                \
    }

    float s1 = 0.f, s2 = 0.f;

    ISSUE(0, 0);
#pragma unroll
    for (int ck = 0; ck < 8; ck++) {
        const int bb = ck & 1;
        // drain-first: zero counting assumptions, race-free by construction
        asm volatile("s_waitcnt vmcnt(0)" ::: "memory");
        __builtin_amdgcn_sched_barrier(0);

        // fix dummy halo rows (block-uniform branch; h edges only)
        if (!h0ok) {
            xstage[bb][wave * 2][0][lane] = 0.f;
            xstage[bb][wave * 2 + 1][0][lane] = 0.f;
        }
        if (!h2ok) {
            xstage[bb][wave * 2][2][lane] = 0.f;
            xstage[bb][wave * 2 + 1][2][lane] = 0.f;
        }

        // prefetch next chunk into the other buffer; flies during conv below
        if (ck < 7) ISSUE(ck + 1, bb ^ 1);

#pragma unroll
        for (int j = 0; j < 2; j++) {
            const int c = ck * 32 + wave * 2 + j;
            const int lc = wave * 2 + j;
            float v0 = xstage[bb][lc][0][lane];
            float v1 = xstage[bb][lc][1][lane];
            float v2 = xstage[bb][lc][2][lane];

            const float* wk = &swdw[c * 9];     // LDS broadcast reads
            float acc = sbdw[c];

            float l0 = __shfl_up(v0, 1);   if (lane == 0)  l0 = 0.f;
            float r0 = __shfl_down(v0, 1); if (lane == 63) r0 = 0.f;
            acc += wk[0] * l0 + wk[1] * v0 + wk[2] * r0;

            float l1 = __shfl_up(v1, 1);   if (lane == 0)  l1 = 0.f;
            float r1 = __shfl_down(v1, 1); if (lane == 63) r1 = 0.f;
            acc += wk[3] * l1 + wk[4] * v1 + wk[5] * r1;

            float l2 = __shfl_up(v2, 1);   if (lane == 0)  l2 = 0.f;
            float r2 = __shfl_down(v2, 1); if (lane == 63) r2 = 0.f;
            acc += wk[6] * l2 + wk[7] * v2 + wk[8] * r2;

            s1 += acc;
            s2 += acc * acc;
            sdw[lane * SDW_STRIDE + c] = f2bf(acc);
            sxr[lane * SDW_STRIDE + c] = f2bf(v1);
        }
    }
#undef ISSUE

    r1s[wave][lane] = s1;
    r2s[wave][lane] = s2;
    __syncthreads();

    // ---- phase 2: LN stats per pixel ----
    if (tid < 64) {
        float a1 = 0.f, a2 = 0.f;
#pragma unroll
        for (int q = 0; q < 16; q++) { a1 += r1s[q][tid]; a2 += r2s[q][tid]; }
        float mu = a1 * (1.0f / 256.0f);
        float var = a2 * (1.0f / 256.0f) - mu * mu;
        mu_s[tid] = mu;
        rs_s[tid] = rsqrtf(var + 1e-5f);
    }
    __syncthreads();

    // ---- phase 3: LN + GELU, in-place into sdw ----
    {
        const int c0 = (tid & 63) * 4;
        float g4[4], b4[4];
#pragma unroll
        for (int i = 0; i < 4; i++) { g4[i] = ln_g[c0 + i]; b4[i] = ln_b[c0 + i]; }
#pragma unroll
        for (int pass = 0; pass < 4; pass++) {
            int w = wave + pass * 16;
            float mu = mu_s[w], rs = rs_s[w];
            unsigned short* row = &sdw[w * SDW_STRIDE + c0];
#pragma unroll
            for (int i = 0; i < 4; i++) {
                float v = (bf2f(row[i]) - mu) * rs * g4[i] + b4[i];
                row[i] = f2bf(0.5f * v * (1.0f + erff(v * 0.70710678118654752f)));
            }
        }
    }
    __syncthreads();

    // ---- phase 4: fused GEMMs from LDS ----
    const int r16  = lane & 15;
    const int quad = lane >> 4;
    const int wm   = wave >> 2;       // m-tile 0..3 (16 pixels each)
    const int wn   = wave & 3;        // n-quarter (4 x 16 cols each)

#define LOAD_A(frag, basep, koff)                                   \
    {                                                               \
        const unsigned short* ap_ = (basep) + (koff);               \
        ((unsigned int*)&(frag))[0] = *(const unsigned int*)&ap_[0];\
        ((unsigned int*)&(frag))[1] = *(const unsigned int*)&ap_[2];\
        ((unsigned int*)&(frag))[2] = *(const unsigned int*)&ap_[4];\
        ((unsigned int*)&(frag))[3] = *(const unsigned int*)&ap_[6];\
    }

    // gemm_in: bf16(x) @ win_t^T + b_in -> xp interior
    {
        f32x4 acc[4];
#pragma unroll
        for (int i = 0; i < 4; i++) acc[i] = (f32x4){0.f, 0.f, 0.f, 0.f};
        const unsigned short* arow = &sxr[(wm * 16 + r16) * SDW_STRIDE];

#pragma unroll
        for (int k0 = 0; k0 < CCH; k0 += 32) {
            bf16x8 a;
            LOAD_A(a, arow, k0 + quad * 8);
#pragma unroll
            for (int i = 0; i < 4; i++) {
                int co = (wn * 4 + i) * 16 + r16;
                bf16x8 bfr = *(const bf16x8*)&win_t[(size_t)co * CCH + k0 + quad * 8];
                acc[i] = __builtin_amdgcn_mfma_f32_16x16x32_bf16(a, bfr, acc[i], 0, 0, 0);
            }
        }

        unsigned short* xprow = xp + (((size_t)n * HIN + (h + 1)) * WIN + 1) * CCH;
#pragma unroll
        for (int i = 0; i < 4; i++) {
            int co = (wn * 4 + i) * 16 + r16;
            float bias = b_in[co];
#pragma unroll
            for (int r = 0; r < 4; r++) {
                int w = wm * 16 + quad * 4 + r;
                xprow[(size_t)w * CCH + co] = f2bf(acc[i][r] + bias);
            }
        }
    }

    // offmask: x1 @ womt^T + bias -> off (fp32), msk (fp32)
    {
        f32x4 acc[4];
#pragma unroll
        for (int i = 0; i < 4; i++) acc[i] = (f32x4){0.f, 0.f, 0.f, 0.f};
        const unsigned short* arow = &sdw[(wm * 16 + r16) * SDW_STRIDE];

#pragma unroll
        for (int k0 = 0; k0 < CCH; k0 += 32) {
            bf16x8 a;
            LOAD_A(a, arow, k0 + quad * 8);
#pragma unroll
            for (int i = 0; i < 4; i++) {
                int col = (wn * 4 + i) * 16 + r16;
                int colc = (col < 216) ? col : 215;   // clamp: safe addr
                bf16x8 bfr = *(const bf16x8*)&womt[(size_t)colc * CCH + k0 + quad * 8];
                acc[i] = __builtin_amdgcn_mfma_f32_16x16x32_bf16(a, bfr, acc[i], 0, 0, 0);
            }
        }

        const int sbase = n * HWSZ + h * WW;
#pragma unroll
        for (int i = 0; i < 4; i++) {
            int col = (wn * 4 + i) * 16 + r16;
            if (col >= 216) continue;
            float bias = (col < 144) ? b_off[col] : b_mask[col - 144];
#pragma unroll
            for (int r = 0; r < 4; r++) {
                int w = wm * 16 + quad * 4 + r;
                int s = sbase + w;
                float v = acc[i][r] + bias;
                if (col < 144) off[(size_t)s * 144 + col] = v;
                else           msk[(size_t)s * 72 + col - 144] = v;
            }
        }
    }
#undef LOAD_A
}

// ---------------------------------------------------------------------------
// Kernel 2 (merged): deformable sampling -> agg in LDS -> output GEMM + BN
// + SiLU. 512 blocks x 512 threads, 32 px/block. (unchanged, passing)
// ---------------------------------------------------------------------------
__device__ __forceinline__ void acc8_tap(float* a, uint4 vv, float wgt) {
    a[0] += wgt * __uint_as_float(vv.x << 16);
    a[1] += wgt * __uint_as_float(vv.x & 0xffff0000u);
    a[2] += wgt * __uint_as_float(vv.y << 16);
    a[3] += wgt * __uint_as_float(vv.y & 0xffff0000u);
    a[4] += wgt * __uint_as_float(vv.z << 16);
    a[5] += wgt * __uint_as_float(vv.z & 0xffff0000u);
    a[6] += wgt * __uint_as_float(vv.w << 16);
    a[7] += wgt * __uint_as_float(vv.w & 0xffff0000u);
}

__global__ __launch_bounds__(512) void k_samp_out(
    const unsigned short* __restrict__ xp, const float* __restrict__ off,
    const float* __restrict__ msk, const unsigned short* __restrict__ wout_t,
    const float* __restrict__ b_out, const float* __restrict__ bn_g,
    const float* __restrict__ bn_b, const float* __restrict__ bn_mean,
    const float* __restrict__ bn_var, float* __restrict__ out)
{
    __shared__ int2   tco[2304];                 // 18432 B
    __shared__ float4 twt[2304];                 // 36864 B
    __shared__ unsigned short agg_l[32 * SDW_STRIDE];  // 16512 B

    const int tid = threadIdx.x;
    const int s0 = blockIdx.x * 32;
    const int n = s0 >> 12;
    const int hw0 = s0 & 4095;

    // ---- phase P: per-(pix,g) softmax + tap prep (threads 0..255) ----
    if (tid < 256) {
        const int pix = tid >> 3, g = tid & 7;
        const int s = s0 + pix;
        const int hw = s & 4095;
        const int h = hw >> 6, w = hw & 63;
        const float* mskp = msk + (size_t)s * 72 + g * 9;
        const float* offp = off + (size_t)s * 144 + g * 18;
        float e[9];
        float mx = -1e30f;
#pragma unroll
        for (int p = 0; p < PP; p++) { e[p] = mskp[p]; mx = fmaxf(mx, e[p]); }
        float sum = 0.f;
#pragma unroll
        for (int p = 0; p < PP; p++) { e[p] = __expf(e[p] - mx); sum += e[p]; }
        float rs = 1.0f / sum;
#pragma unroll
        for (int p = 0; p < PP; p++) {
            float m = e[p] * rs;
            float ox = offp[p * 2], oy = offp[p * 2 + 1];
            int i = p / 3, j = p - i * 3;
            float fx = (float)(w + i) + ox;
            float fy = (float)(h + j) + oy;
            float x0f = floorf(fx), y0f = floorf(fy);
            int x0 = (int)x0f, y0 = (int)y0f;
            float wx = fx - x0f, wy = fy - y0f;
            float w00 = (1.f - wx) * (1.f - wy) * m;
            float w10 = wx * (1.f - wy) * m;
            float w01 = (1.f - wx) * wy * m;
            float w11 = wx * wy * m;
            int x1c = x0 + 1, y1c = y0 + 1;
            if (!((x0  >= 0) && (x0  < WIN))) { w00 = 0.f; w01 = 0.f; }
            if (!((x1c >= 0) && (x1c < WIN))) { w10 = 0.f; w11 = 0.f; }
            if (!((y0  >= 0) && (y0  < HIN))) { w00 = 0.f; w10 = 0.f; }
            if (!((y1c >= 0) && (y1c < HIN))) { w01 = 0.f; w11 = 0.f; }
            int cx0 = min(max(x0, 0), WIN - 1), cx1 = min(max(x1c, 0), WIN - 1);
            int cy0 = min(max(y0, 0), HIN - 1), cy1 = min(max(y1c, 0), HIN - 1);
            tco[tid * 9 + p] = make_int2(cx0 | (cx1 << 16), cy0 | (cy1 << 16));
            twt[tid * 9 + p] = make_float4(w00, w10, w01, w11);
        }
    }
    __syncthreads();

    // ---- phase T: taps, 2 passes of 16 px ----
    const int l5 = tid & 31;
    const int g = l5 >> 2, c8 = l5 & 3;
    const unsigned short* base = xp + (size_t)n * HIN * WIN * CCH + g * GCH + c8 * 8;

#pragma unroll
    for (int pp = 0; pp < 2; pp++) {
        const int pix = pp * 16 + (tid >> 5);
        const int tbase = pix * 72 + g * 9;

        float a[8];
#pragma unroll
        for (int i = 0; i < 8; i++) a[i] = 0.f;

#pragma unroll
        for (int p = 0; p < PP; p++) {
            int2 cc = tco[tbase + p];
            float4 wt = twt[tbase + p];
            int cx0 = cc.x & 0xFFFF, cx1 = cc.x >> 16;
            int cy0 = cc.y & 0xFFFF, cy1 = cc.y >> 16;
            const unsigned short* r0 = base + (size_t)(cy0 * WIN) * CCH;
            const unsigned short* r1 = base + (size_t)(cy1 * WIN) * CCH;
            uint4 v00 = *(const uint4*)&r0[(size_t)cx0 * CCH];
            uint4 v10 = *(const uint4*)&r0[(size_t)cx1 * CCH];
            uint4 v01 = *(const uint4*)&r1[(size_t)cx0 * CCH];
            uint4 v11 = *(const uint4*)&r1[(size_t)cx1 * CCH];
            acc8_tap(a, v00, wt.x);
            acc8_tap(a, v10, wt.y);
            acc8_tap(a, v01, wt.z);
            acc8_tap(a, v11, wt.w);
        }

        unsigned int* dst = (unsigned int*)&agg_l[pix * SDW_STRIDE + g * GCH + c8 * 8];
        dst[0] = (unsigned int)f2bf(a[0]) | ((unsigned int)f2bf(a[1]) << 16);
        dst[1] = (unsigned int)f2bf(a[2]) | ((unsigned int)f2bf(a[3]) << 16);
        dst[2] = (unsigned int)f2bf(a[4]) | ((unsigned int)f2bf(a[5]) << 16);
        dst[3] = (unsigned int)f2bf(a[6]) | ((unsigned int)f2bf(a[7]) << 16);
    }
    __syncthreads();

    // ---- phase G: 32x256 GEMM from LDS-agg + BN + SiLU -> out ----
    {
        const int wave = tid >> 6;        // 0..7
        const int lane = tid & 63;
        const int r16  = lane & 15;
        const int quad = lane >> 4;
        const int wm   = wave >> 2;       // m-tile 0..1 (16 px each)
        const int wn   = wave & 3;        // 64-col group

        f32x4 acc[4];
#pragma unroll
        for (int i = 0; i < 4; i++) acc[i] = (f32x4){0.f, 0.f, 0.f, 0.f};

        const unsigned short* arow = &agg_l[(wm * 16 + r16) * SDW_STRIDE];

#pragma unroll
        for (int k0 = 0; k0 < CCH; k0 += 32) {
            bf16x8 a;
            {
                const unsigned short* ap_ = arow + k0 + quad * 8;
                ((unsigned int*)&a)[0] = *(const unsigned int*)&ap_[0];
                ((unsigned int*)&a)[1] = *(const unsigned int*)&ap_[2];
                ((unsigned int*)&a)[2] = *(const unsigned int*)&ap_[4];
                ((unsigned int*)&a)[3] = *(const unsigned int*)&ap_[6];
            }
#pragma unroll
            for (int nt = 0; nt < 4; nt++) {
                int co = wn * 64 + nt * 16 + r16;
                bf16x8 bfr = *(const bf16x8*)&wout_t[(size_t)co * CCH + k0 + quad * 8];
                acc[nt] = __builtin_amdgcn_mfma_f32_16x16x32_bf16(a, bfr, acc[nt], 0, 0, 0);
            }
        }

#pragma unroll
        for (int nt = 0; nt < 4; nt++) {
            int co = wn * 64 + nt * 16 + r16;
            float mean = bn_mean[co];
            float rstd = rsqrtf(bn_var[co] + 1e-5f);
            float gg = bn_g[co], bb = bn_b[co], bo = b_out[co];
            int hwb = hw0 + wm * 16 + quad * 4;
            float tmp[4];
#pragma unroll
            for (int r = 0; r < 4; r++) {
                float y = acc[nt][r] + bo;
                float yh = (y - mean) * rstd * gg + bb;
                tmp[r] = yh / (1.0f + __expf(-yh));
            }
            float4 v = make_float4(tmp[0], tmp[1], tmp[2], tmp[3]);
            *(float4*)&out[((size_t)n * CCH + co) * HWSZ + hwb] = v;
        }
    }
}

// ---------------------------------------------------------------------------
extern "C" void kernel_launch(void* const* d_in, const int* in_sizes, int n_in,
                              void* d_out, int out_size, void* d_ws, size_t ws_size,
                              hipStream_t stream)
{
    const float* x       = (const float*)d_in[0];
    const float* w_in    = (const float*)d_in[1];
    const float* b_in    = (const float*)d_in[2];
    const float* w_dw    = (const float*)d_in[3];
    const float* b_dw    = (const float*)d_in[4];
    const float* ln_g    = (const float*)d_in[5];
    const float* ln_b    = (const float*)d_in[6];
    const float* w_off   = (const float*)d_in[7];
    const float* b_off   = (const float*)d_in[8];
    const float* w_mask  = (const float*)d_in[9];
    const float* b_mask  = (const float*)d_in[10];
    const float* w_out   = (const float*)d_in[11];
    const float* b_out   = (const float*)d_in[12];
    const float* bn_g    = (const float*)d_in[13];
    const float* bn_b    = (const float*)d_in[14];
    const float* bn_mean = (const float*)d_in[15];
    const float* bn_var  = (const float*)d_in[16];
    float* out = (float*)d_out;

    unsigned short* xp     = (unsigned short*)d_ws;
    unsigned short* win_t  = xp + XP_ELEMS;
    unsigned short* wout_t = win_t + WINT_ELEMS;
    unsigned short* womt   = wout_t + WOUTT_ELEMS;
    float* off = (float*)(womt + WOMT_ELEMS);
    float* msk = off + OFF_ELEMS;
    // total ~24 MB

    k_prep<<<dim3(128), 256, 0, stream>>>(w_in, w_off, w_mask, w_out,
                                          win_t, womt, wout_t, xp);
    k_dw_fused<<<dim3(256), 1024, 0, stream>>>(x, w_dw, b_dw, ln_g, ln_b, b_in,
                                               win_t, womt, b_off, b_mask,
                                               xp, off, msk);
    k_samp_out<<<dim3(512), 512, 0, stream>>>(xp, off, msk, wout_t, b_out,
                                              bn_g, bn_b, bn_mean, bn_var, out);
}